// Round 3
// baseline (60.115 us; speedup 1.0000x reference)
//
#include <hip/hip_runtime.h>
#include <hip/hip_bf16.h>

// Problem constants (fixed by setup_inputs: num_views=8, bs=4096, c=2048).
#define NV    8
#define BSZ   4096
#define CCH   2048
#define NPAIR 28          // NV*(NV-1)/2
#define NACC  36          // NV*(NV+1)/2 (upper triangle incl. diagonal)
#define BLK   256
#define VSTR  ((size_t)BSZ * CCH)   // float stride between views

typedef float f32x4 __attribute__((ext_vector_type(4)));   // native vector: OK for nontemporal builtins

// index of (v,w), v<=w, in the packed upper-triangular enumeration
__device__ __forceinline__ constexpr int triIdx(int v, int w) {
    return v * NV - (v * (v - 1)) / 2 + (w - v);
}

// One WAVE per batch row: 64 lanes, each lane owns 32 channels (8 j-steps of
// float4). No LDS, no __syncthreads.
__global__ __launch_bounds__(BLK, 4) void interviews_kernel(
        const float* __restrict__ in, float* __restrict__ out) {
    const int lane = threadIdx.x & 63;
    const int wv   = threadIdx.x >> 6;
    const int b    = blockIdx.x * (BLK / 64) + wv;   // batch row, 0..BSZ-1

    float acc[NACC];
#pragma unroll
    for (int i = 0; i < NACC; ++i) acc[i] = 0.0f;

    // view v, batch b, channel c lives at in[v*VSTR + b*CCH + c]
    const float* base = in + (size_t)b * CCH + (size_t)lane * 4;

    // 2048 channels / (64 lanes * 4 floats) = 8 iterations
#pragma unroll 2
    for (int j = 0; j < CCH / (64 * 4); ++j) {
        f32x4 x[NV];
#pragma unroll
        for (int v = 0; v < NV; ++v) {
            const f32x4* p = reinterpret_cast<const f32x4*>(
                base + (size_t)v * VSTR + (size_t)j * 256);
            x[v] = __builtin_nontemporal_load(p);
        }
        int idx = 0;
#pragma unroll
        for (int v = 0; v < NV; ++v) {
#pragma unroll
            for (int w = v; w < NV; ++w) {
                acc[idx] += x[v][0] * x[w][0] + x[v][1] * x[w][1]
                          + x[v][2] * x[w][2] + x[v][3] * x[w][3];
                ++idx;
            }
        }
    }

    // full-wave butterfly reduction; all lanes end with the complete sums
#pragma unroll
    for (int i = 0; i < NACC; ++i) {
        float v = acc[i];
#pragma unroll
        for (int off = 1; off < 64; off <<= 1)
            v += __shfl_xor(v, off, 64);
        acc[i] = v;
    }

    if (lane == 0) {
        float rn[NV];
#pragma unroll
        for (int v = 0; v < NV; ++v)
            rn[v] = 1.0f / sqrtf(acc[triIdx(v, v)]);

        float s[NPAIR];
        float mean = 0.0f;
        int k = 0;
#pragma unroll
        for (int v = 0; v < NV; ++v) {
#pragma unroll
            for (int w = v + 1; w < NV; ++w) {
                s[k] = acc[triIdx(v, w)] * rn[v] * rn[w];
                mean += s[k];
                ++k;
            }
        }
        mean *= (1.0f / NPAIR);

        float var = 0.0f;
#pragma unroll
        for (int i = 0; i < NPAIR; ++i) {
            float d = s[i] - mean;
            var += d * d;
        }
        var *= (1.0f / (NPAIR - 1));   // ddof=1

        out[b] = -var;
    }
}

extern "C" void kernel_launch(void* const* d_in, const int* in_sizes, int n_in,
                              void* d_out, int out_size, void* d_ws, size_t ws_size,
                              hipStream_t stream) {
    const float* in = (const float*)d_in[0];
    float* out = (float*)d_out;
    // out_size == BSZ (4096); one wave per batch row, 4 waves per block
    interviews_kernel<<<dim3(out_size / (BLK / 64)), dim3(BLK), 0, stream>>>(in, out);
}

// Round 4
// 57.671 us; speedup vs baseline: 1.0424x; 1.0424x over previous
//
#include <hip/hip_runtime.h>
#include <hip/hip_bf16.h>

// Problem constants (fixed by setup_inputs: num_views=8, bs=4096, c=2048).
#define NV    8
#define BSZ   4096
#define CCH   2048
#define NPAIR 28          // NV*(NV-1)/2
#define NACC  36          // NV*(NV+1)/2 (upper triangle incl. diagonal)
#define BLK   256
#define BPB   2           // batches per block (sequential)
#define VSTR  ((size_t)BSZ * CCH)   // float stride between views

// index of (v,w), v<=w, in the packed upper-triangular enumeration
__device__ __forceinline__ constexpr int triIdx(int v, int w) {
    return v * NV - (v * (v - 1)) / 2 + (w - v);
}

__global__ __launch_bounds__(BLK) void interviews_kernel(
        const float* __restrict__ in, float* __restrict__ out) {
    const int t = threadIdx.x;
    const int wave = t >> 6;
    const int lane = t & 63;

    __shared__ float red[BLK / 64][NACC];

    for (int bb = 0; bb < BPB; ++bb) {
        const int b = blockIdx.x * BPB + bb;   // batch row, 0..BSZ-1

        float acc[NACC];
#pragma unroll
        for (int i = 0; i < NACC; ++i) acc[i] = 0.0f;

        // view v, batch b, channel c lives at in[v*VSTR + b*CCH + c]
        const float* base = in + (size_t)b * CCH;

        // 2048 channels / (256 threads * 4 floats) = 2 iterations
#pragma unroll
        for (int j = 0; j < CCH / (BLK * 4); ++j) {
            float4 x[NV];
#pragma unroll
            for (int v = 0; v < NV; ++v) {
                const float* p = base + (size_t)v * VSTR + (size_t)j * BLK * 4 + (size_t)t * 4;
                x[v] = *reinterpret_cast<const float4*>(p);
            }
            int idx = 0;
#pragma unroll
            for (int v = 0; v < NV; ++v) {
#pragma unroll
                for (int w = v; w < NV; ++w) {
                    acc[idx] += x[v].x * x[w].x + x[v].y * x[w].y
                              + x[v].z * x[w].z + x[v].w * x[w].w;
                    ++idx;
                }
            }
        }

        // wave-level tree reduction (wave = 64 lanes)
#pragma unroll
        for (int i = 0; i < NACC; ++i) {
            float v = acc[i];
#pragma unroll
            for (int off = 32; off > 0; off >>= 1)
                v += __shfl_down(v, off, 64);
            acc[i] = v;
        }

        if (bb > 0) __syncthreads();   // red[] reuse across iterations
        if (lane == 0) {
#pragma unroll
            for (int i = 0; i < NACC; ++i) red[wave][i] = acc[i];
        }
        __syncthreads();

        if (t == 0) {
            float G[NACC];
#pragma unroll
            for (int i = 0; i < NACC; ++i)
                G[i] = red[0][i] + red[1][i] + red[2][i] + red[3][i];

            float rn[NV];
#pragma unroll
            for (int v = 0; v < NV; ++v)
                rn[v] = 1.0f / sqrtf(G[triIdx(v, v)]);

            float s[NPAIR];
            float mean = 0.0f;
            int k = 0;
#pragma unroll
            for (int v = 0; v < NV; ++v) {
#pragma unroll
                for (int w = v + 1; w < NV; ++w) {
                    s[k] = G[triIdx(v, w)] * rn[v] * rn[w];
                    mean += s[k];
                    ++k;
                }
            }
            mean *= (1.0f / NPAIR);

            float var = 0.0f;
#pragma unroll
            for (int i = 0; i < NPAIR; ++i) {
                float d = s[i] - mean;
                var += d * d;
            }
            var *= (1.0f / (NPAIR - 1));   // ddof=1

            out[b] = -var;
        }
    }
}

extern "C" void kernel_launch(void* const* d_in, const int* in_sizes, int n_in,
                              void* d_out, int out_size, void* d_ws, size_t ws_size,
                              hipStream_t stream) {
    const float* in = (const float*)d_in[0];
    float* out = (float*)d_out;
    // out_size == BSZ (4096); one block per BPB batch rows
    interviews_kernel<<<dim3(out_size / BPB), dim3(BLK), 0, stream>>>(in, out);
}

// Round 5
// 51.161 us; speedup vs baseline: 1.1750x; 1.1273x over previous
//
#include <hip/hip_runtime.h>
#include <hip/hip_bf16.h>

// Problem constants (fixed by setup_inputs: num_views=8, bs=4096, c=2048).
#define NV    8
#define BSZ   4096
#define CCH   2048
#define NPAIR 28          // NV*(NV-1)/2
#define NACC  36          // NV*(NV+1)/2 (upper triangle incl. diagonal)
#define BLK   128         // 2 waves per block -> 8 resident blocks/CU at ~120 VGPR
#define VSTR  ((size_t)BSZ * CCH)   // float stride between views

// index of (v,w), v<=w, in the packed upper-triangular enumeration
__device__ __forceinline__ constexpr int triIdx(int v, int w) {
    return v * NV - (v * (v - 1)) / 2 + (w - v);
}

__global__ __launch_bounds__(BLK) void interviews_kernel(
        const float* __restrict__ in, float* __restrict__ out) {
    const int b = blockIdx.x;     // batch row, 0..BSZ-1
    const int t = threadIdx.x;
    const int wave = t >> 6;
    const int lane = t & 63;

    float acc[NACC];
#pragma unroll
    for (int i = 0; i < NACC; ++i) acc[i] = 0.0f;

    // view v, batch b, channel c lives at in[v*VSTR + b*CCH + c]
    const float* base = in + (size_t)b * CCH;

    // 2048 channels / (128 threads * 4 floats) = 4 iterations; unroll 2 keeps
    // 16 float4 (64 VGPR) of load data in flight — same pressure as R0.
#pragma unroll 2
    for (int j = 0; j < CCH / (BLK * 4); ++j) {
        float4 x[NV];
#pragma unroll
        for (int v = 0; v < NV; ++v) {
            const float* p = base + (size_t)v * VSTR + (size_t)j * BLK * 4 + (size_t)t * 4;
            x[v] = *reinterpret_cast<const float4*>(p);
        }
        int idx = 0;
#pragma unroll
        for (int v = 0; v < NV; ++v) {
#pragma unroll
            for (int w = v; w < NV; ++w) {
                acc[idx] += x[v].x * x[w].x + x[v].y * x[w].y
                          + x[v].z * x[w].z + x[v].w * x[w].w;
                ++idx;
            }
        }
    }

    // wave-level tree reduction (wave = 64 lanes)
#pragma unroll
    for (int i = 0; i < NACC; ++i) {
        float v = acc[i];
#pragma unroll
        for (int off = 32; off > 0; off >>= 1)
            v += __shfl_down(v, off, 64);
        acc[i] = v;
    }

    __shared__ float red[BLK / 64][NACC];
    if (lane == 0) {
#pragma unroll
        for (int i = 0; i < NACC; ++i) red[wave][i] = acc[i];
    }
    __syncthreads();

    if (t == 0) {
        float G[NACC];
#pragma unroll
        for (int i = 0; i < NACC; ++i)
            G[i] = red[0][i] + red[1][i];

        float rn[NV];
#pragma unroll
        for (int v = 0; v < NV; ++v)
            rn[v] = 1.0f / sqrtf(G[triIdx(v, v)]);

        float s[NPAIR];
        float mean = 0.0f;
        int k = 0;
#pragma unroll
        for (int v = 0; v < NV; ++v) {
#pragma unroll
            for (int w = v + 1; w < NV; ++w) {
                s[k] = G[triIdx(v, w)] * rn[v] * rn[w];
                mean += s[k];
                ++k;
            }
        }
        mean *= (1.0f / NPAIR);

        float var = 0.0f;
#pragma unroll
        for (int i = 0; i < NPAIR; ++i) {
            float d = s[i] - mean;
            var += d * d;
        }
        var *= (1.0f / (NPAIR - 1));   // ddof=1

        out[b] = -var;
    }
}

extern "C" void kernel_launch(void* const* d_in, const int* in_sizes, int n_in,
                              void* d_out, int out_size, void* d_ws, size_t ws_size,
                              hipStream_t stream) {
    const float* in = (const float*)d_in[0];
    float* out = (float*)d_out;
    // out_size == BSZ (4096); one 128-thread block per batch row
    interviews_kernel<<<dim3(out_size), dim3(BLK), 0, stream>>>(in, out);
}

// Round 6
// 46.576 us; speedup vs baseline: 1.2907x; 1.0984x over previous
//
#include <hip/hip_runtime.h>
#include <hip/hip_bf16.h>

// Problem constants (fixed by setup_inputs: num_views=8, bs=4096, c=2048).
#define NV    8
#define BSZ   4096
#define CCH   2048
#define NPAIR 28          // NV*(NV-1)/2
#define NACC  36          // NV*(NV+1)/2 (upper triangle incl. diagonal)
#define BLK   64          // ONE wave per block; one block per batch row
#define VSTR  ((size_t)BSZ * CCH)   // float stride between views

// index of (v,w), v<=w, in the packed upper-triangular enumeration
__device__ __forceinline__ constexpr int triIdx(int v, int w) {
    return v * NV - (v * (v - 1)) / 2 + (w - v);
}

// One wave per batch row: no LDS, no __syncthreads, 216-shuffle reduce
// amortized over the full 64 KB batch stream.
__global__ __launch_bounds__(BLK) void interviews_kernel(
        const float* __restrict__ in, float* __restrict__ out) {
    const int b    = blockIdx.x;      // batch row, 0..BSZ-1
    const int lane = threadIdx.x;     // 0..63

    float acc[NACC];
#pragma unroll
    for (int i = 0; i < NACC; ++i) acc[i] = 0.0f;

    // view v, batch b, channel c lives at in[v*VSTR + b*CCH + c]
    const float* base = in + (size_t)b * CCH + (size_t)lane * 4;

    // 2048 channels / (64 lanes * 4 floats) = 8 iterations; unroll 2 keeps
    // 16 float4 (64 VGPR) of load data in flight.
#pragma unroll 2
    for (int j = 0; j < CCH / (BLK * 4); ++j) {
        float4 x[NV];
#pragma unroll
        for (int v = 0; v < NV; ++v) {
            const float* p = base + (size_t)v * VSTR + (size_t)j * BLK * 4;
            x[v] = *reinterpret_cast<const float4*>(p);
        }
        int idx = 0;
#pragma unroll
        for (int v = 0; v < NV; ++v) {
#pragma unroll
            for (int w = v; w < NV; ++w) {
                acc[idx] += x[v].x * x[w].x + x[v].y * x[w].y
                          + x[v].z * x[w].z + x[v].w * x[w].w;
                ++idx;
            }
        }
    }

    // full-wave butterfly reduction; all lanes end with the complete sums
#pragma unroll
    for (int i = 0; i < NACC; ++i) {
        float v = acc[i];
#pragma unroll
        for (int off = 1; off < 64; off <<= 1)
            v += __shfl_xor(v, off, 64);
        acc[i] = v;
    }

    if (lane == 0) {
        float rn[NV];
#pragma unroll
        for (int v = 0; v < NV; ++v)
            rn[v] = 1.0f / sqrtf(acc[triIdx(v, v)]);

        float s[NPAIR];
        float mean = 0.0f;
        int k = 0;
#pragma unroll
        for (int v = 0; v < NV; ++v) {
#pragma unroll
            for (int w = v + 1; w < NV; ++w) {
                s[k] = acc[triIdx(v, w)] * rn[v] * rn[w];
                mean += s[k];
                ++k;
            }
        }
        mean *= (1.0f / NPAIR);

        float var = 0.0f;
#pragma unroll
        for (int i = 0; i < NPAIR; ++i) {
            float d = s[i] - mean;
            var += d * d;
        }
        var *= (1.0f / (NPAIR - 1));   // ddof=1

        out[b] = -var;
    }
}

extern "C" void kernel_launch(void* const* d_in, const int* in_sizes, int n_in,
                              void* d_out, int out_size, void* d_ws, size_t ws_size,
                              hipStream_t stream) {
    const float* in = (const float*)d_in[0];
    float* out = (float*)d_out;
    // out_size == BSZ (4096); one 64-thread block (one wave) per batch row
    interviews_kernel<<<dim3(out_size), dim3(BLK), 0, stream>>>(in, out);
}